// Round 1
// baseline (76.963 us; speedup 1.0000x reference)
//
#include <hip/hip_runtime.h>
#include <math.h>

#define NUM_EXPERTS 32
#define INPUT_DIM   1024
#define BATCH       8192

// ---------------------------------------------------------------------------
// Kernel 1: w_sum[e,i] = sum_o W[e,i,o]  (W is [E, I, O] row-major, O contig)
// One 64-lane wave per (e,i) row; block = 256 threads = 4 rows.
// Pure streaming reduction: float4 loads, wave shuffle reduce.
// ---------------------------------------------------------------------------
__global__ __launch_bounds__(256) void wsum_kernel(const float* __restrict__ W,
                                                   float* __restrict__ wsum) {
    const int gwave = (blockIdx.x * blockDim.x + threadIdx.x) >> 6;  // row id
    const int lane  = threadIdx.x & 63;
    if (gwave >= NUM_EXPERTS * INPUT_DIM) return;

    const float4* row = (const float4*)(W + (size_t)gwave * INPUT_DIM);
    float s0 = 0.f, s1 = 0.f, s2 = 0.f, s3 = 0.f;
#pragma unroll
    for (int k = 0; k < 4; ++k) {             // 256 float4 per row / 64 lanes
        float4 v = row[lane + 64 * k];
        s0 += v.x; s1 += v.y; s2 += v.z; s3 += v.w;
    }
    float s = (s0 + s1) + (s2 + s3);
#pragma unroll
    for (int off = 32; off >= 1; off >>= 1)
        s += __shfl_xor(s, off, 64);
    if (lane == 0) wsum[gwave] = s;
}

// ---------------------------------------------------------------------------
// Kernel 2: per-token gating (logits -> softmax -> top2) + combine.
// One block (256 thr = 4 waves) per token.
// ---------------------------------------------------------------------------
__global__ __launch_bounds__(256) void moe_kernel(
    const float* __restrict__ x,        // [B, I]
    const float* __restrict__ wsum,     // [E, I]   (from workspace)
    const float* __restrict__ bias,     // [E, I]   (E,O with O==I)
    const float* __restrict__ gw,       // [E, I]   gate weight
    const float* __restrict__ gb,       // [E]      gate bias
    float* __restrict__ out)            // [B, I]
{
    __shared__ float xs[INPUT_DIM];
    __shared__ float logits[NUM_EXPERTS];
    __shared__ float selv[2];
    __shared__ int   sele[2];

    const int b = blockIdx.x;
    const int t = threadIdx.x;

    // stage x row in LDS (and keep our float4 in regs for the combine)
    const float4 xv = ((const float4*)(x + (size_t)b * INPUT_DIM))[t];
    ((float4*)xs)[t] = xv;
    __syncthreads();

    // gating logits: wave w handles experts [8w, 8w+8)
    const int wave = t >> 6;
    const int lane = t & 63;
#pragma unroll
    for (int e8 = 0; e8 < 8; ++e8) {
        const int e = wave * 8 + e8;
        const float* g = gw + (size_t)e * INPUT_DIM;
        float acc = 0.f;
#pragma unroll
        for (int j = 0; j < 16; ++j)
            acc = fmaf(xs[lane + 64 * j], g[lane + 64 * j], acc);
#pragma unroll
        for (int off = 32; off >= 1; off >>= 1)
            acc += __shfl_xor(acc, off, 64);
        if (lane == 0) logits[e] = acc + gb[e];
    }
    __syncthreads();

    // softmax + top-2 (serial on one thread; 32 elements, ties -> lowest idx)
    if (t == 0) {
        float m = logits[0];
#pragma unroll
        for (int e = 1; e < NUM_EXPERTS; ++e) m = fmaxf(m, logits[e]);
        float denom = 0.f;
#pragma unroll
        for (int e = 0; e < NUM_EXPERTS; ++e) denom += expf(logits[e] - m);

        int e0 = 0; float l0 = logits[0];
#pragma unroll
        for (int e = 1; e < NUM_EXPERTS; ++e)
            if (logits[e] > l0) { l0 = logits[e]; e0 = e; }
        int e1 = -1; float l1 = -INFINITY;
#pragma unroll
        for (int e = 0; e < NUM_EXPERTS; ++e)
            if (e != e0 && logits[e] > l1) { l1 = logits[e]; e1 = e; }

        const float inv = 1.0f / denom;
        selv[0] = expf(l0 - m) * inv;
        selv[1] = expf(l1 - m) * inv;
        sele[0] = e0;
        sele[1] = e1;
    }
    __syncthreads();

    const float v0 = selv[0], v1 = selv[1];
    const int   e0 = sele[0], e1 = sele[1];

    // combine: out = v0*(x*ws0 + b0) + v1*(x*ws1 + b1)
    const float4 w0 = ((const float4*)(wsum + (size_t)e0 * INPUT_DIM))[t];
    const float4 w1 = ((const float4*)(wsum + (size_t)e1 * INPUT_DIM))[t];
    const float4 c0 = ((const float4*)(bias + (size_t)e0 * INPUT_DIM))[t];
    const float4 c1 = ((const float4*)(bias + (size_t)e1 * INPUT_DIM))[t];

    float4 o;
    o.x = fmaf(v0, fmaf(xv.x, w0.x, c0.x), v1 * fmaf(xv.x, w1.x, c1.x));
    o.y = fmaf(v0, fmaf(xv.y, w0.y, c0.y), v1 * fmaf(xv.y, w1.y, c1.y));
    o.z = fmaf(v0, fmaf(xv.z, w0.z, c0.z), v1 * fmaf(xv.z, w1.z, c1.z));
    o.w = fmaf(v0, fmaf(xv.w, w0.w, c0.w), v1 * fmaf(xv.w, w1.w, c1.w));
    ((float4*)(out + (size_t)b * INPUT_DIM))[t] = o;
}

// ---------------------------------------------------------------------------
extern "C" void kernel_launch(void* const* d_in, const int* in_sizes, int n_in,
                              void* d_out, int out_size, void* d_ws, size_t ws_size,
                              hipStream_t stream) {
    const float* x    = (const float*)d_in[0];   // [B, I]
    const float* W    = (const float*)d_in[1];   // [E, I, O]
    const float* bias = (const float*)d_in[2];   // [E, O]
    const float* gw   = (const float*)d_in[3];   // [E, I]
    const float* gb   = (const float*)d_in[4];   // [E]
    // d_in[5] = topk (scalar 2, hardcoded)

    float* wsum = (float*)d_ws;                  // [E, I] = 128 KiB
    float* out  = (float*)d_out;

    // Stage 1: row sums of W  (32768 rows, 4 rows per 256-thr block)
    wsum_kernel<<<(NUM_EXPERTS * INPUT_DIM) / 4, 256, 0, stream>>>(W, wsum);

    // Stage 2+3: gating + combine, one block per token
    moe_kernel<<<BATCH, 256, 0, stream>>>(x, wsum, bias, gw, gb, out);
}

// Round 2
// 57.836 us; speedup vs baseline: 1.3307x; 1.3307x over previous
//
#include <hip/hip_runtime.h>
#include <math.h>

#define NE 32            // experts
#define DIM 1024         // input dim == output dim
#define NB 8192          // batch
#define F4ROW (DIM / 4)  // 256 float4 per row

#define GATE_BLOCKS 512                  // 16 tokens per block, 4 per wave
#define WSUM_BLOCKS ((NE * DIM) / 4)     // 8192 blocks, 4 rows each (1/wave)

// ---------------------------------------------------------------------------
// Launch 1: fused  (a) gating -> top2 per token   [blocks 0..GATE_BLOCKS)
//                  (b) w_sum[e,i] = sum_o W[e,i,o] [blocks GATE_BLOCKS..)
// Gating blocks come FIRST so they co-schedule under the HBM-bound wsum
// streaming (~27 us of W reads hides all gating compute + gw L2 traffic).
// ---------------------------------------------------------------------------
__global__ __launch_bounds__(256) void stage1_kernel(
    const float* __restrict__ W,     // [E, I, O]
    const float* __restrict__ x,     // [B, I]
    const float* __restrict__ gw,    // [E, I]
    const float* __restrict__ gb,    // [E]
    float* __restrict__ wsum,        // [E, I]   ws
    float* __restrict__ topv,        // [B, 2]   ws
    int*   __restrict__ tope)        // [B, 2]   ws
{
    const int wave = threadIdx.x >> 6;
    const int lane = threadIdx.x & 63;

    if (blockIdx.x >= GATE_BLOCKS) {
        // ---- wsum: one row per wave, 4 KB contiguous stream per wave ----
        const int r = (blockIdx.x - GATE_BLOCKS) * 4 + wave;
        const float4* row = (const float4*)(W + (size_t)r * DIM);
        float4 a = row[lane], b = row[lane + 64], c = row[lane + 128], d = row[lane + 192];
        float s = ((a.x + a.y) + (a.z + a.w)) + ((b.x + b.y) + (b.z + b.w)) +
                  ((c.x + c.y) + (c.z + c.w)) + ((d.x + d.y) + (d.z + d.w));
#pragma unroll
        for (int off = 32; off >= 1; off >>= 1) s += __shfl_xor(s, off, 64);
        if (lane == 0) wsum[r] = s;
        return;
    }

    // ---- gating: 4 tokens per wave, x rows held in registers ----
    __shared__ float logits[16][NE];
    const int tbase = blockIdx.x * 16 + wave * 4;

    const float4* x4 = (const float4*)x;
    float4 xq[4][4];
#pragma unroll
    for (int tk = 0; tk < 4; ++tk)
#pragma unroll
        for (int j = 0; j < 4; ++j)
            xq[tk][j] = x4[(size_t)(tbase + tk) * F4ROW + lane + 64 * j];

    const float4* gw4 = (const float4*)gw;
#pragma unroll 4
    for (int e = 0; e < NE; ++e) {
        const float4 g0 = gw4[(size_t)e * F4ROW + lane];
        const float4 g1 = gw4[(size_t)e * F4ROW + lane + 64];
        const float4 g2 = gw4[(size_t)e * F4ROW + lane + 128];
        const float4 g3 = gw4[(size_t)e * F4ROW + lane + 192];

        float acc[4];
#pragma unroll
        for (int tk = 0; tk < 4; ++tk) {
            float a = 0.f;
            a = fmaf(xq[tk][0].x, g0.x, a); a = fmaf(xq[tk][0].y, g0.y, a);
            a = fmaf(xq[tk][0].z, g0.z, a); a = fmaf(xq[tk][0].w, g0.w, a);
            a = fmaf(xq[tk][1].x, g1.x, a); a = fmaf(xq[tk][1].y, g1.y, a);
            a = fmaf(xq[tk][1].z, g1.z, a); a = fmaf(xq[tk][1].w, g1.w, a);
            a = fmaf(xq[tk][2].x, g2.x, a); a = fmaf(xq[tk][2].y, g2.y, a);
            a = fmaf(xq[tk][2].z, g2.z, a); a = fmaf(xq[tk][2].w, g2.w, a);
            a = fmaf(xq[tk][3].x, g3.x, a); a = fmaf(xq[tk][3].y, g3.y, a);
            a = fmaf(xq[tk][3].z, g3.z, a); a = fmaf(xq[tk][3].w, g3.w, a);
            acc[tk] = a;
        }
#pragma unroll
        for (int off = 32; off >= 1; off >>= 1) {
            acc[0] += __shfl_xor(acc[0], off, 64);
            acc[1] += __shfl_xor(acc[1], off, 64);
            acc[2] += __shfl_xor(acc[2], off, 64);
            acc[3] += __shfl_xor(acc[3], off, 64);
        }
        if (lane == 0) {
            const float gbe = gb[e];
            logits[wave * 4 + 0][e] = acc[0] + gbe;
            logits[wave * 4 + 1][e] = acc[1] + gbe;
            logits[wave * 4 + 2][e] = acc[2] + gbe;
            logits[wave * 4 + 3][e] = acc[3] + gbe;
        }
    }
    __syncthreads();

    // per-token softmax + top2 (lanes 0..3 of each wave, one token each)
    if (lane < 4) {
        const int tok = tbase + lane;
        const float* L = logits[wave * 4 + lane];

        float m = L[0];
#pragma unroll
        for (int e = 1; e < NE; ++e) m = fmaxf(m, L[e]);
        float denom = 0.f;
#pragma unroll
        for (int e = 0; e < NE; ++e) denom += expf(L[e] - m);

        int e0 = 0; float l0 = L[0];
#pragma unroll
        for (int e = 1; e < NE; ++e)
            if (L[e] > l0) { l0 = L[e]; e0 = e; }
        int e1 = -1; float l1 = -INFINITY;
#pragma unroll
        for (int e = 0; e < NE; ++e)
            if (e != e0 && L[e] > l1) { l1 = L[e]; e1 = e; }

        const float inv = 1.0f / denom;
        topv[tok * 2 + 0] = expf(l0 - m) * inv;
        topv[tok * 2 + 1] = expf(l1 - m) * inv;
        tope[tok * 2 + 0] = e0;
        tope[tok * 2 + 1] = e1;
    }
}

// ---------------------------------------------------------------------------
// Launch 2: combine.  One token per wave, 4 waves/block.
// out = v0*(x*ws[e0] + bias[e0]) + v1*(x*ws[e1] + bias[e1])
// ---------------------------------------------------------------------------
__global__ __launch_bounds__(256) void combine_kernel(
    const float* __restrict__ x,
    const float* __restrict__ wsum,
    const float* __restrict__ bias,
    const float* __restrict__ topv,
    const int*   __restrict__ tope,
    float* __restrict__ out)
{
    const int wave = threadIdx.x >> 6;
    const int lane = threadIdx.x & 63;
    const int tok  = blockIdx.x * 4 + wave;

    const float v0 = topv[tok * 2 + 0];
    const float v1 = topv[tok * 2 + 1];
    const int   e0 = tope[tok * 2 + 0];
    const int   e1 = tope[tok * 2 + 1];

    const float4* x4 = (const float4*)(x    + (size_t)tok * DIM);
    const float4* w0 = (const float4*)(wsum + (size_t)e0  * DIM);
    const float4* w1 = (const float4*)(wsum + (size_t)e1  * DIM);
    const float4* b0 = (const float4*)(bias + (size_t)e0  * DIM);
    const float4* b1 = (const float4*)(bias + (size_t)e1  * DIM);
    float4*       o4 = (float4*)(out + (size_t)tok * DIM);

#pragma unroll
    for (int j = 0; j < 4; ++j) {
        const int idx = lane + 64 * j;
        const float4 xv = x4[idx];
        const float4 a0 = w0[idx], a1 = w1[idx];
        const float4 c0 = b0[idx], c1 = b1[idx];
        float4 o;
        o.x = fmaf(v0, fmaf(xv.x, a0.x, c0.x), v1 * fmaf(xv.x, a1.x, c1.x));
        o.y = fmaf(v0, fmaf(xv.y, a0.y, c0.y), v1 * fmaf(xv.y, a1.y, c1.y));
        o.z = fmaf(v0, fmaf(xv.z, a0.z, c0.z), v1 * fmaf(xv.z, a1.z, c1.z));
        o.w = fmaf(v0, fmaf(xv.w, a0.w, c0.w), v1 * fmaf(xv.w, a1.w, c1.w));
        o4[idx] = o;
    }
}

// ---------------------------------------------------------------------------
extern "C" void kernel_launch(void* const* d_in, const int* in_sizes, int n_in,
                              void* d_out, int out_size, void* d_ws, size_t ws_size,
                              hipStream_t stream) {
    const float* x    = (const float*)d_in[0];   // [B, I]
    const float* W    = (const float*)d_in[1];   // [E, I, O]
    const float* bias = (const float*)d_in[2];   // [E, O]
    const float* gw   = (const float*)d_in[3];   // [E, I]
    const float* gb   = (const float*)d_in[4];   // [E]
    // d_in[5] = topk (always 2, hardcoded)

    float* wsum = (float*)d_ws;                       // 128 KiB
    float* topv = wsum + (size_t)NE * DIM;            // 64 KiB
    int*   tope = (int*)(topv + (size_t)NB * 2);      // 64 KiB
    float* out  = (float*)d_out;

    stage1_kernel<<<GATE_BLOCKS + WSUM_BLOCKS, 256, 0, stream>>>(
        W, x, gw, gb, wsum, topv, tope);

    combine_kernel<<<NB / 4, 256, 0, stream>>>(x, wsum, bias, topv, tope, out);
}